// Round 4
// baseline (15422.972 us; speedup 1.0000x reference)
//
#include <hip/hip_runtime.h>
#include <hip/hip_bf16.h>
#include <cstdint>

typedef __bf16 bf16;
typedef __bf16 bf16x8 __attribute__((ext_vector_type(8)));
typedef float  f32x4  __attribute__((ext_vector_type(4)));

#define D_DIM   1024
#define ND      3072
#define B_SZ    32
#define U_SZ    512
#define T_SZ    513
#define M_REAL  (B_SZ * T_SZ)   // 16416
#define WXS_LD  1032            // padded k-stride -> 2-way LDS banking (free)
#define A_LD    1032

__device__ __forceinline__ f32x4 mfma16(bf16x8 a, bf16x8 b, f32x4 c) {
    return __builtin_amdgcn_mfma_f32_16x16x32_bf16(a, b, c, 0, 0, 0);
}

struct bfpair { bf16x8 hi, lo; };

// split 8 consecutive fp32 into bf16 hi + bf16 residual lo
__device__ __forceinline__ bfpair split8(const float* p) {
    f32x4 a = *(const f32x4*)p;
    f32x4 b = *(const f32x4*)(p + 4);
    bfpair r;
#pragma unroll
    for (int j = 0; j < 4; ++j) {
        r.hi[j] = (bf16)a[j];
        r.lo[j] = (bf16)(a[j] - (float)r.hi[j]);
        r.hi[4 + j] = (bf16)b[j];
        r.lo[4 + j] = (bf16)(b[j] - (float)r.hi[4 + j]);
    }
    return r;
}

// convert 8 consecutive fp32 to bf16 (round-to-nearest via cast)
__device__ __forceinline__ bf16x8 cvt8(const float* p) {
    f32x4 a = *(const f32x4*)p;
    f32x4 b = *(const f32x4*)(p + 4);
    bf16x8 r;
#pragma unroll
    for (int j = 0; j < 4; ++j) { r[j] = (bf16)a[j]; r[4 + j] = (bf16)b[j]; }
    return r;
}

// ---------------------------------------------------------------------------
// Transpose fp32 Wd [K][N] -> bf16 hi/lo planes WdT[N][K]
// ---------------------------------------------------------------------------
__global__ void transpose_split(const float* __restrict__ in,
                                bf16* __restrict__ out_hi, bf16* __restrict__ out_lo,
                                int R, int C) {
    __shared__ float tile[32][33];
    const int c0 = blockIdx.x * 32, r0 = blockIdx.y * 32;
    const int tx = threadIdx.x, ty = threadIdx.y;   // 32 x 8
    for (int i = 0; i < 32; i += 8)
        tile[ty + i][tx] = in[(size_t)(r0 + ty + i) * C + c0 + tx];
    __syncthreads();
    for (int i = 0; i < 32; i += 8) {
        const float v  = tile[tx][ty + i];
        const bf16  hi = (bf16)v;
        out_hi[(size_t)(c0 + ty + i) * R + r0 + tx] = hi;
        out_lo[(size_t)(c0 + ty + i) * R + r0 + tx] = (bf16)(v - (float)hi);
    }
}

// ---------------------------------------------------------------------------
// GRU scan. 128 persistent WGs x 256 threads; block = (mhalf, 16-dim slice).
//   Waves 0..2: hp = h_{t-1} @ Wh gate-slice; A split hi/lo (2 MFMAs/k-step),
//               Wh slice gathered once into 128 VGPRs (bf16).
//   Wave 3:     xp(t+1) = embed[tok] @ Wx slice (bf16, slice in LDS), one step
//               ahead into parity-buffered LDS.
//   h history: fp32 rows of d_out (row b*513+t), later overwritten in place
//   by the output GEMM. Cross-block publish via device-scope counter barrier.
// ---------------------------------------------------------------------------
__global__ __launch_bounds__(256, 1)
void gru_scan(const float* __restrict__ Wx,    const float* __restrict__ Wh,
              const float* __restrict__ bx,    const float* __restrict__ bh,
              const float* __restrict__ h0,    const float* __restrict__ embed,
              const int* __restrict__ y,       float* __restrict__ ghs,
              int* __restrict__ flags)
{
    __shared__ __align__(16) bf16 WxS[48 * WXS_LD];  // [c = gate*16+cl][k]
    __shared__ float hpx[48 * 17];
    __shared__ float xpx[2][48 * 17];
    __shared__ float bhs[48], bxs[48];

    const int tid  = threadIdx.x;
    const int wave = tid >> 6, lane = tid & 63;
    const int quad = lane >> 4, l15 = lane & 15;
    const int mhalf = blockIdx.x & 1;
    const int n0 = (blockIdx.x >> 1) * 16;
    const int nblocks = gridDim.x;

    // ---- one-time: gather Wx slice [48 cols][1024 k] from fp32 Wx[k][3D] ----
    for (int idx = tid; idx < 3 * 1024 * 16; idx += 256) {
        const int cl = idx & 15;
        const int k  = (idx >> 4) & 1023;
        const int g  = idx >> 14;            // 0..2
        WxS[(g * 16 + cl) * WXS_LD + k] = (bf16)Wx[(size_t)k * ND + g * D_DIM + n0 + cl];
    }
    if (tid < 48) {
        bhs[tid] = bh[(tid >> 4) * D_DIM + n0 + (tid & 15)];
        bxs[tid] = bx[(tid >> 4) * D_DIM + n0 + (tid & 15)];
    }

    // ---- one-time: gather Wh gate-slice into registers (waves 0..2) ----
    // breg[ks][j] = Wh[k = ks*32 + quad*8 + j][gate*1024 + n0 + l15]
    bf16x8 breg[32];
    if (wave < 3) {
#pragma unroll
        for (int ks = 0; ks < 32; ++ks) {
            bf16x8 v;
#pragma unroll
            for (int j = 0; j < 8; ++j)
                v[j] = (bf16)Wh[(size_t)(ks * 32 + quad * 8 + j) * ND
                                + wave * D_DIM + n0 + l15];
            breg[ks] = v;
        }
    }

    // gate-phase identity: one (batch, dim) output per thread
    const int gml = tid >> 4, nl = tid & 15;
    const int gb  = mhalf * 16 + gml;
    const int gn  = n0 + nl;
    float hold = h0[gn];

    __syncthreads();

    // ---- pre-loop: xp(0), all tokens NULL (embed row 0) -> xpx[0] ----
    if (wave == 3) {
        const float* xrow = embed + quad * 8;
        f32x4 ax0 = {}, ax1 = {}, ax2 = {};
#pragma unroll
        for (int ks = 0; ks < 32; ++ks) {
            bf16x8 xa = cvt8(xrow + ks * 32);
            bf16x8 w0 = *(const bf16x8*)(WxS + (l15)      * WXS_LD + ks * 32 + quad * 8);
            bf16x8 w1 = *(const bf16x8*)(WxS + (16 + l15) * WXS_LD + ks * 32 + quad * 8);
            bf16x8 w2 = *(const bf16x8*)(WxS + (32 + l15) * WXS_LD + ks * 32 + quad * 8);
            ax0 = mfma16(xa, w0, ax0);
            ax1 = mfma16(xa, w1, ax1);
            ax2 = mfma16(xa, w2, ax2);
        }
#pragma unroll
        for (int i = 0; i < 4; ++i) {
            xpx[0][(quad * 4 + i) * 17 + l15]      = ax0[i];
            xpx[0][(16 + quad * 4 + i) * 17 + l15] = ax1[i];
            xpx[0][(32 + quad * 4 + i) * 17 + l15] = ax2[i];
        }
    }

    for (int t = 0; t < T_SZ; ++t) {
        // ---- waves 0..2: hp = h_{t-1} @ Wh slice, split-precision A ----
        if (wave < 3) {
            const float* hrow = (t == 0)
                ? (h0 + quad * 8)
                : (ghs + ((size_t)(mhalf * 16 + l15) * T_SZ + (t - 1)) * D_DIM + quad * 8);
            f32x4 a0 = {}, a1 = {};
#pragma unroll
            for (int ks = 0; ks < 32; ++ks) {
                bfpair h8 = split8(hrow + ks * 32);
                a0 = mfma16(h8.hi, breg[ks], a0);
                a1 = mfma16(h8.lo, breg[ks], a1);
            }
            a0 = a0 + a1;
#pragma unroll
            for (int i = 0; i < 4; ++i)
                hpx[(wave * 16 + quad * 4 + i) * 17 + l15] = a0[i];
        }

        // ---- wave 3: xp(t+1), off critical path ----
        if (wave == 3 && t < U_SZ) {
            const int tok = y[(mhalf * 16 + l15) * U_SZ + t] & 1023;  // token at step t+1
            const float* xrow = embed + (size_t)tok * D_DIM + quad * 8;
            const int p = (t + 1) & 1;
            f32x4 ax0 = {}, ax1 = {}, ax2 = {};
#pragma unroll
            for (int ks = 0; ks < 32; ++ks) {
                bf16x8 xa = cvt8(xrow + ks * 32);
                bf16x8 w0 = *(const bf16x8*)(WxS + (l15)      * WXS_LD + ks * 32 + quad * 8);
                bf16x8 w1 = *(const bf16x8*)(WxS + (16 + l15) * WXS_LD + ks * 32 + quad * 8);
                bf16x8 w2 = *(const bf16x8*)(WxS + (32 + l15) * WXS_LD + ks * 32 + quad * 8);
                ax0 = mfma16(xa, w0, ax0);
                ax1 = mfma16(xa, w1, ax1);
                ax2 = mfma16(xa, w2, ax2);
            }
#pragma unroll
            for (int i = 0; i < 4; ++i) {
                xpx[p][(quad * 4 + i) * 17 + l15]      = ax0[i];
                xpx[p][(16 + quad * 4 + i) * 17 + l15] = ax1[i];
                xpx[p][(32 + quad * 4 + i) * 17 + l15] = ax2[i];
            }
        }
        __syncthreads();

        // ---- gates: one (gb, gn) per thread ----
        {
            const int p = t & 1;
            const float xz = xpx[p][(gml)      * 17 + nl] + bxs[nl];
            const float xr = xpx[p][(16 + gml) * 17 + nl] + bxs[16 + nl];
            const float xh = xpx[p][(32 + gml) * 17 + nl] + bxs[32 + nl];
            const float hz = hpx[(gml)      * 17 + nl] + bhs[nl];
            const float hr = hpx[(16 + gml) * 17 + nl] + bhs[16 + nl];
            const float hh = hpx[(32 + gml) * 17 + nl] + bhs[32 + nl];
            const float z  = 1.f / (1.f + __expf(-(xz + hz)));
            const float r  = 1.f / (1.f + __expf(-(xr + hr)));
            const float pa = xh + r * hh;
            const float hc = 1.f - 2.f / (__expf(2.f * pa) + 1.f);   // tanh(pa)
            const float hn = z * hold + (1.f - z) * hc;
            hold = hn;
            ghs[((size_t)gb * T_SZ + t) * D_DIM + gn] = hn;          // fp32 h row
        }

        // ---- device-scope barrier: publish h_t ----
        if (t + 1 < T_SZ) {
            __threadfence();          // release
            __syncthreads();
            if (tid == 0) {
                __hip_atomic_fetch_add(flags + t, 1, __ATOMIC_RELEASE,
                                       __HIP_MEMORY_SCOPE_AGENT);
                while (__hip_atomic_load(flags + t, __ATOMIC_ACQUIRE,
                                         __HIP_MEMORY_SCOPE_AGENT) < nblocks)
                    __builtin_amdgcn_s_sleep(1);
            }
            __syncthreads();
            __threadfence();          // acquire
        }
    }
}

// ---------------------------------------------------------------------------
// In-place row-block GEMM: C_rows(fp32) = C_rows @ Wd + bd.
// Block owns 32 disjoint rows; stages them (split hi/lo bf16) into LDS before
// overwriting. 3-term split-precision MFMA: Ah*Bh + Al*Bh + Ah*Bl.
// ---------------------------------------------------------------------------
__global__ __launch_bounds__(256, 1)
void gemm_rows_inplace(float* __restrict__ C,
                       const bf16* __restrict__ WdTh, const bf16* __restrict__ WdTl,
                       const float* __restrict__ bd)
{
    __shared__ __align__(16) bf16 Ah[32 * A_LD];
    __shared__ __align__(16) bf16 Al[32 * A_LD];
    const int tid  = threadIdx.x;
    const int wave = tid >> 6, lane = tid & 63;
    const int quad = lane >> 4, l15 = lane & 15;
    const size_t r0 = (size_t)blockIdx.x * 32;

    // stage A rows (32 x 1024 fp32 -> hi/lo bf16), coalesced 32B chunks
    for (int idx = tid; idx < 32 * 128; idx += 256) {
        const int r = idx >> 7, ch = idx & 127;
        bfpair p = split8(C + (r0 + r) * D_DIM + ch * 8);
        *(bf16x8*)(Ah + r * A_LD + ch * 8) = p.hi;
        *(bf16x8*)(Al + r * A_LD + ch * 8) = p.lo;
    }
    __syncthreads();

    // wave owns 256 output cols: n = wave*256 + nt*16 + l15
    f32x4 acc[2][16] = {};
    const int nbase = wave * 256;
    for (int ks = 0; ks < 32; ++ks) {
        bf16x8 a0h = *(const bf16x8*)(Ah + (l15)      * A_LD + ks * 32 + quad * 8);
        bf16x8 a0l = *(const bf16x8*)(Al + (l15)      * A_LD + ks * 32 + quad * 8);
        bf16x8 a1h = *(const bf16x8*)(Ah + (16 + l15) * A_LD + ks * 32 + quad * 8);
        bf16x8 a1l = *(const bf16x8*)(Al + (16 + l15) * A_LD + ks * 32 + quad * 8);
#pragma unroll
        for (int nt = 0; nt < 16; ++nt) {
            const size_t boff = (size_t)(nbase + nt * 16 + l15) * D_DIM + ks * 32 + quad * 8;
            bf16x8 bhv = *(const bf16x8*)(WdTh + boff);
            bf16x8 blv = *(const bf16x8*)(WdTl + boff);
            acc[0][nt] = mfma16(a0h, bhv, acc[0][nt]);
            acc[0][nt] = mfma16(a0l, bhv, acc[0][nt]);
            acc[0][nt] = mfma16(a0h, blv, acc[0][nt]);
            acc[1][nt] = mfma16(a1h, bhv, acc[1][nt]);
            acc[1][nt] = mfma16(a1l, bhv, acc[1][nt]);
            acc[1][nt] = mfma16(a1h, blv, acc[1][nt]);
        }
    }

    // epilogue: row = r0 + mt*16 + quad*4 + i, col = nbase + nt*16 + l15
#pragma unroll
    for (int nt = 0; nt < 16; ++nt) {
        const int col = nbase + nt * 16 + l15;
        const float bvl = bd[col];
#pragma unroll
        for (int mt = 0; mt < 2; ++mt)
#pragma unroll
            for (int i = 0; i < 4; ++i)
                C[(r0 + mt * 16 + quad * 4 + i) * D_DIM + col] =
                    acc[mt][nt][i] + bvl;
    }
}

// ---------------------------------------------------------------------------
extern "C" void kernel_launch(void* const* d_in, const int* in_sizes, int n_in,
                              void* d_out, int out_size, void* d_ws, size_t ws_size,
                              hipStream_t stream) {
    (void)in_sizes; (void)n_in; (void)out_size; (void)ws_size;
    const int*   y     = (const int*)  d_in[0];
    const float* embed = (const float*)d_in[1];
    const float* Wx    = (const float*)d_in[2];
    const float* Wh    = (const float*)d_in[3];
    const float* bx    = (const float*)d_in[4];
    const float* bh    = (const float*)d_in[5];
    const float* Wd    = (const float*)d_in[6];
    const float* bd    = (const float*)d_in[7];
    const float* h0    = (const float*)d_in[8];
    float* out = (float*)d_out;

    // workspace: WdT hi/lo (2+2 MB) + flags (2 KB)
    bf16* WdTh = (bf16*)d_ws;
    bf16* WdTl = WdTh + (size_t)D_DIM * D_DIM;
    int* flags = (int*)((char*)d_ws + (size_t)D_DIM * D_DIM * 4);

    hipMemsetAsync(flags, 0, 2048, stream);

    transpose_split<<<dim3(D_DIM / 32, D_DIM / 32), dim3(32, 8), 0, stream>>>(
        Wd, WdTh, WdTl, D_DIM, D_DIM);

    // GRU scan with fused input projections; fp32 h history -> d_out rows
    gru_scan<<<128, 256, 0, stream>>>(Wx, Wh, bx, bh, h0, embed, y, out, flags);

    // In-place: out rows = h rows @ Wd + bd
    gemm_rows_inplace<<<M_REAL / 32, 256, 0, stream>>>(out, WdTh, WdTl, bd);
}

// Round 5
// 7731.742 us; speedup vs baseline: 1.9948x; 1.9948x over previous
//
#include <hip/hip_runtime.h>
#include <hip/hip_bf16.h>
#include <cstdint>

typedef __bf16 bf16;
typedef __bf16 bf16x8 __attribute__((ext_vector_type(8)));
typedef float  f32x4  __attribute__((ext_vector_type(4)));
typedef uint32_t u32x4 __attribute__((ext_vector_type(4)));

#define D_DIM   1024
#define ND      3072
#define B_SZ    32
#define U_SZ    512
#define T_SZ    513
#define M_REAL  (B_SZ * T_SZ)   // 16416
#define WXS_LD  1032            // padded k-stride -> 2-way LDS banking (free)
#define A_LD    1032

__device__ __forceinline__ f32x4 mfma16(bf16x8 a, bf16x8 b, f32x4 c) {
    return __builtin_amdgcn_mfma_f32_16x16x32_bf16(a, b, c, 0, 0, 0);
}

struct bfpair { bf16x8 hi, lo; };

// split 8 consecutive fp32 into bf16 hi + bf16 residual lo
__device__ __forceinline__ bfpair split8(const float* p) {
    f32x4 a = *(const f32x4*)p;
    f32x4 b = *(const f32x4*)(p + 4);
    bfpair r;
#pragma unroll
    for (int j = 0; j < 4; ++j) {
        r.hi[j] = (bf16)a[j];
        r.lo[j] = (bf16)(a[j] - (float)r.hi[j]);
        r.hi[4 + j] = (bf16)b[j];
        r.lo[4 + j] = (bf16)(b[j] - (float)r.hi[4 + j]);
    }
    return r;
}

// convert 8 consecutive fp32 to bf16
__device__ __forceinline__ bf16x8 cvt8(const float* p) {
    f32x4 a = *(const f32x4*)p;
    f32x4 b = *(const f32x4*)(p + 4);
    bf16x8 r;
#pragma unroll
    for (int j = 0; j < 4; ++j) { r[j] = (bf16)a[j]; r[4 + j] = (bf16)b[j]; }
    return r;
}

// unpack 8 packed uint32 (hi bf16 | lo bf16 << 16) -> hi8, lo8 via v_perm
__device__ __forceinline__ bfpair unpack8(const uint32_t* p) {
    u32x4 a = *(const u32x4*)p;
    u32x4 b = *(const u32x4*)(p + 4);
    union { uint32_t u[4]; bf16x8 v; } H, L;
    H.u[0] = __builtin_amdgcn_perm(a.y, a.x, 0x05040100u);
    H.u[1] = __builtin_amdgcn_perm(a.w, a.z, 0x05040100u);
    H.u[2] = __builtin_amdgcn_perm(b.y, b.x, 0x05040100u);
    H.u[3] = __builtin_amdgcn_perm(b.w, b.z, 0x05040100u);
    L.u[0] = __builtin_amdgcn_perm(a.y, a.x, 0x07060302u);
    L.u[1] = __builtin_amdgcn_perm(a.w, a.z, 0x07060302u);
    L.u[2] = __builtin_amdgcn_perm(b.y, b.x, 0x07060302u);
    L.u[3] = __builtin_amdgcn_perm(b.w, b.z, 0x07060302u);
    bfpair r; r.hi = H.v; r.lo = L.v;
    return r;
}

// ---------------------------------------------------------------------------
// Transpose fp32 Wd [K][N] -> bf16 hi/lo planes WdT[N][K]
// ---------------------------------------------------------------------------
__global__ void transpose_split(const float* __restrict__ in,
                                bf16* __restrict__ out_hi, bf16* __restrict__ out_lo,
                                int R, int C) {
    __shared__ float tile[32][33];
    const int c0 = blockIdx.x * 32, r0 = blockIdx.y * 32;
    const int tx = threadIdx.x, ty = threadIdx.y;   // 32 x 8
    for (int i = 0; i < 32; i += 8)
        tile[ty + i][tx] = in[(size_t)(r0 + ty + i) * C + c0 + tx];
    __syncthreads();
    for (int i = 0; i < 32; i += 8) {
        const float v  = tile[tx][ty + i];
        const bf16  hi = (bf16)v;
        out_hi[(size_t)(c0 + ty + i) * R + r0 + tx] = hi;
        out_lo[(size_t)(c0 + ty + i) * R + r0 + tx] = (bf16)(v - (float)hi);
    }
}

// ---------------------------------------------------------------------------
// GRU scan. 128 persistent WGs x 256 threads; block = (mhalf, 16-dim slice).
//   Waves 0..2: hp = h_{t-1} @ Wh gate-slice (Wh slice in 128 VGPRs).
//   Wave 3:     xp(t+1) one step ahead into parity-buffered LDS.
//   h history: PACKED (bf16 hi | bf16 lo<<16) uint32 in d_out rows, published
//   via agent-scope atomic_exchange (write-through to coherence point).
//   Plain vector loads read it: every (b,t) address is written once and first
//   read strictly after the barrier -> no stale cache copy can exist -> NO
//   threadfence (the R4 fences' L2 tag-walks were ~26 us/step).
// ---------------------------------------------------------------------------
__global__ __launch_bounds__(256, 1)
void gru_scan(const float* __restrict__ Wx,    const float* __restrict__ Wh,
              const float* __restrict__ bx,    const float* __restrict__ bh,
              const float* __restrict__ h0,    const float* __restrict__ embed,
              const int* __restrict__ y,       uint32_t* __restrict__ ghs,
              int* __restrict__ flags)
{
    __shared__ __align__(16) bf16 WxS[48 * WXS_LD];  // [c = gate*16+cl][k]
    __shared__ float hpx[48 * 17];
    __shared__ float xpx[2][48 * 17];
    __shared__ float bhs[48], bxs[48];

    const int tid  = threadIdx.x;
    const int wave = tid >> 6, lane = tid & 63;
    const int quad = lane >> 4, l15 = lane & 15;
    const int mhalf = blockIdx.x & 1;
    const int n0 = (blockIdx.x >> 1) * 16;
    const int nblocks = gridDim.x;
    int* cnt = flags;          // [0..511]
    int* go  = flags + 512;    // [0..511]

    // ---- one-time: gather Wx slice [48 cols][1024 k] from fp32 Wx[k][3D] ----
    for (int idx = tid; idx < 3 * 1024 * 16; idx += 256) {
        const int cl = idx & 15;
        const int k  = (idx >> 4) & 1023;
        const int g  = idx >> 14;            // 0..2
        WxS[(g * 16 + cl) * WXS_LD + k] = (bf16)Wx[(size_t)k * ND + g * D_DIM + n0 + cl];
    }
    if (tid < 48) {
        bhs[tid] = bh[(tid >> 4) * D_DIM + n0 + (tid & 15)];
        bxs[tid] = bx[(tid >> 4) * D_DIM + n0 + (tid & 15)];
    }

    // ---- one-time: gather Wh gate-slice into registers (waves 0..2) ----
    bf16x8 breg[32];
    if (wave < 3) {
#pragma unroll
        for (int ks = 0; ks < 32; ++ks) {
            bf16x8 v;
#pragma unroll
            for (int j = 0; j < 8; ++j)
                v[j] = (bf16)Wh[(size_t)(ks * 32 + quad * 8 + j) * ND
                                + wave * D_DIM + n0 + l15];
            breg[ks] = v;
        }
    }

    // gate-phase identity: one (batch, dim) output per thread
    const int gml = tid >> 4, nl = tid & 15;
    const int gb  = mhalf * 16 + gml;
    const int gn  = n0 + nl;
    float hold = h0[gn];
    uint32_t pkjunk = 0;

    __syncthreads();

    // ---- pre-loop: xp(0), all tokens NULL (embed row 0) -> xpx[0] ----
    if (wave == 3) {
        const float* xrow = embed + quad * 8;
        f32x4 ax0 = {}, ax1 = {}, ax2 = {};
#pragma unroll
        for (int ks = 0; ks < 32; ++ks) {
            bf16x8 xa = cvt8(xrow + ks * 32);
            bf16x8 w0 = *(const bf16x8*)(WxS + (l15)      * WXS_LD + ks * 32 + quad * 8);
            bf16x8 w1 = *(const bf16x8*)(WxS + (16 + l15) * WXS_LD + ks * 32 + quad * 8);
            bf16x8 w2 = *(const bf16x8*)(WxS + (32 + l15) * WXS_LD + ks * 32 + quad * 8);
            ax0 = mfma16(xa, w0, ax0);
            ax1 = mfma16(xa, w1, ax1);
            ax2 = mfma16(xa, w2, ax2);
        }
#pragma unroll
        for (int i = 0; i < 4; ++i) {
            xpx[0][(quad * 4 + i) * 17 + l15]      = ax0[i];
            xpx[0][(16 + quad * 4 + i) * 17 + l15] = ax1[i];
            xpx[0][(32 + quad * 4 + i) * 17 + l15] = ax2[i];
        }
    }

    for (int t = 0; t < T_SZ; ++t) {
        // ---- waves 0..2: hp = h_{t-1} @ Wh slice, split-precision A ----
        if (wave < 3) {
            f32x4 a0 = {}, a1 = {};
            if (t == 0) {
                const float* hrow = h0 + quad * 8;
#pragma unroll
                for (int ks = 0; ks < 32; ++ks) {
                    bfpair h8 = split8(hrow + ks * 32);
                    a0 = mfma16(h8.hi, breg[ks], a0);
                    a1 = mfma16(h8.lo, breg[ks], a1);
                }
            } else {
                const uint32_t* hrow = ghs
                    + ((size_t)(mhalf * 16 + l15) * T_SZ + (t - 1)) * D_DIM + quad * 8;
#pragma unroll
                for (int ks = 0; ks < 32; ++ks) {
                    bfpair h8 = unpack8(hrow + ks * 32);
                    a0 = mfma16(h8.hi, breg[ks], a0);
                    a1 = mfma16(h8.lo, breg[ks], a1);
                }
            }
            a0 = a0 + a1;
#pragma unroll
            for (int i = 0; i < 4; ++i)
                hpx[(wave * 16 + quad * 4 + i) * 17 + l15] = a0[i];
        }

        // ---- wave 3: xp(t+1), off critical path ----
        if (wave == 3 && t < U_SZ) {
            const int tok = y[(mhalf * 16 + l15) * U_SZ + t] & 1023;  // token at step t+1
            const float* xrow = embed + (size_t)tok * D_DIM + quad * 8;
            const int p = (t + 1) & 1;
            f32x4 ax0 = {}, ax1 = {}, ax2 = {};
#pragma unroll
            for (int ks = 0; ks < 32; ++ks) {
                bf16x8 xa = cvt8(xrow + ks * 32);
                bf16x8 w0 = *(const bf16x8*)(WxS + (l15)      * WXS_LD + ks * 32 + quad * 8);
                bf16x8 w1 = *(const bf16x8*)(WxS + (16 + l15) * WXS_LD + ks * 32 + quad * 8);
                bf16x8 w2 = *(const bf16x8*)(WxS + (32 + l15) * WXS_LD + ks * 32 + quad * 8);
                ax0 = mfma16(xa, w0, ax0);
                ax1 = mfma16(xa, w1, ax1);
                ax2 = mfma16(xa, w2, ax2);
            }
#pragma unroll
            for (int i = 0; i < 4; ++i) {
                xpx[p][(quad * 4 + i) * 17 + l15]      = ax0[i];
                xpx[p][(16 + quad * 4 + i) * 17 + l15] = ax1[i];
                xpx[p][(32 + quad * 4 + i) * 17 + l15] = ax2[i];
            }
        }
        __syncthreads();

        // ---- gates: one (gb, gn) per thread; publish packed hi/lo h ----
        {
            const int p = t & 1;
            const float xz = xpx[p][(gml)      * 17 + nl] + bxs[nl];
            const float xr = xpx[p][(16 + gml) * 17 + nl] + bxs[16 + nl];
            const float xh = xpx[p][(32 + gml) * 17 + nl] + bxs[32 + nl];
            const float hz = hpx[(gml)      * 17 + nl] + bhs[nl];
            const float hr = hpx[(16 + gml) * 17 + nl] + bhs[16 + nl];
            const float hh = hpx[(32 + gml) * 17 + nl] + bhs[32 + nl];
            const float z  = 1.f / (1.f + __expf(-(xz + hz)));
            const float r  = 1.f / (1.f + __expf(-(xr + hr)));
            const float pa = xh + r * hh;
            const float hc = 1.f - 2.f / (__expf(2.f * pa) + 1.f);   // tanh(pa)
            const float hn = z * hold + (1.f - z) * hc;
            hold = hn;
            union { uint16_t u[2]; uint32_t w; } pk;
            const bf16 hi = (bf16)hn;
            const bf16 lo = (bf16)(hn - (float)hi);
            pk.u[0] = __builtin_bit_cast(uint16_t, hi);
            pk.u[1] = __builtin_bit_cast(uint16_t, lo);
            // agent-scope exchange: write-through to coherence point; consuming
            // the return value forces the returning form (vmcnt covers arrival)
            uint32_t old = __hip_atomic_exchange(
                ghs + ((size_t)gb * T_SZ + t) * D_DIM + gn, pk.w,
                __ATOMIC_RELAXED, __HIP_MEMORY_SCOPE_AGENT);
            pkjunk ^= old;
        }

        // ---- fence-free device barrier: publish h_t ----
        if (t + 1 < T_SZ) {
            __syncthreads();   // compiler emits s_waitcnt vmcnt(0) first: drains exchanges
            if (tid == 0) {
                const int c = __hip_atomic_fetch_add(cnt + t, 1, __ATOMIC_RELAXED,
                                                     __HIP_MEMORY_SCOPE_AGENT);
                if (c == nblocks - 1) {
                    __hip_atomic_store(go + t, 1, __ATOMIC_RELAXED,
                                       __HIP_MEMORY_SCOPE_AGENT);
                } else {
                    while (!__hip_atomic_load(go + t, __ATOMIC_RELAXED,
                                              __HIP_MEMORY_SCOPE_AGENT))
                        __builtin_amdgcn_s_sleep(1);
                }
            }
            __syncthreads();
        }
    }

    // consume pkjunk so the exchanges keep their returning (sc0) form
    if (pkjunk == 0xDEADBEEFu) flags[1023] = 1;
}

// ---------------------------------------------------------------------------
// In-place row-block GEMM: rows (packed hi/lo h) -> fp32 out rows.
// Block owns 32 disjoint rows; stages them (unpacked to hi/lo bf16) into LDS
// before overwriting. 3-term split-precision: Ah*Bh + Al*Bh + Ah*Bl.
// ---------------------------------------------------------------------------
__global__ __launch_bounds__(256, 1)
void gemm_rows_inplace(float* __restrict__ C,
                       const bf16* __restrict__ WdTh, const bf16* __restrict__ WdTl,
                       const float* __restrict__ bd)
{
    __shared__ __align__(16) bf16 Ah[32 * A_LD];
    __shared__ __align__(16) bf16 Al[32 * A_LD];
    const int tid  = threadIdx.x;
    const int wave = tid >> 6, lane = tid & 63;
    const int quad = lane >> 4, l15 = lane & 15;
    const size_t r0 = (size_t)blockIdx.x * 32;
    const uint32_t* Cw = (const uint32_t*)C;

    // stage A rows (32 x 1024 packed -> hi/lo bf16), coalesced 32B chunks
    for (int idx = tid; idx < 32 * 128; idx += 256) {
        const int r = idx >> 7, ch = idx & 127;
        bfpair p = unpack8(Cw + (r0 + r) * D_DIM + ch * 8);
        *(bf16x8*)(Ah + r * A_LD + ch * 8) = p.hi;
        *(bf16x8*)(Al + r * A_LD + ch * 8) = p.lo;
    }
    __syncthreads();

    // wave owns 256 output cols: n = wave*256 + nt*16 + l15
    f32x4 acc[2][16] = {};
    const int nbase = wave * 256;
    for (int ks = 0; ks < 32; ++ks) {
        bf16x8 a0h = *(const bf16x8*)(Ah + (l15)      * A_LD + ks * 32 + quad * 8);
        bf16x8 a0l = *(const bf16x8*)(Al + (l15)      * A_LD + ks * 32 + quad * 8);
        bf16x8 a1h = *(const bf16x8*)(Ah + (16 + l15) * A_LD + ks * 32 + quad * 8);
        bf16x8 a1l = *(const bf16x8*)(Al + (16 + l15) * A_LD + ks * 32 + quad * 8);
#pragma unroll
        for (int nt = 0; nt < 16; ++nt) {
            const size_t boff = (size_t)(nbase + nt * 16 + l15) * D_DIM + ks * 32 + quad * 8;
            bf16x8 bhv = *(const bf16x8*)(WdTh + boff);
            bf16x8 blv = *(const bf16x8*)(WdTl + boff);
            acc[0][nt] = mfma16(a0h, bhv, acc[0][nt]);
            acc[0][nt] = mfma16(a0l, bhv, acc[0][nt]);
            acc[0][nt] = mfma16(a0h, blv, acc[0][nt]);
            acc[1][nt] = mfma16(a1h, bhv, acc[1][nt]);
            acc[1][nt] = mfma16(a1l, bhv, acc[1][nt]);
            acc[1][nt] = mfma16(a1h, blv, acc[1][nt]);
        }
    }

    // epilogue: row = r0 + mt*16 + quad*4 + i, col = nbase + nt*16 + l15
#pragma unroll
    for (int nt = 0; nt < 16; ++nt) {
        const int col = nbase + nt * 16 + l15;
        const float bvl = bd[col];
#pragma unroll
        for (int mt = 0; mt < 2; ++mt)
#pragma unroll
            for (int i = 0; i < 4; ++i)
                C[(r0 + mt * 16 + quad * 4 + i) * D_DIM + col] =
                    acc[mt][nt][i] + bvl;
    }
}

// ---------------------------------------------------------------------------
extern "C" void kernel_launch(void* const* d_in, const int* in_sizes, int n_in,
                              void* d_out, int out_size, void* d_ws, size_t ws_size,
                              hipStream_t stream) {
    (void)in_sizes; (void)n_in; (void)out_size; (void)ws_size;
    const int*   y     = (const int*)  d_in[0];
    const float* embed = (const float*)d_in[1];
    const float* Wx    = (const float*)d_in[2];
    const float* Wh    = (const float*)d_in[3];
    const float* bx    = (const float*)d_in[4];
    const float* bh    = (const float*)d_in[5];
    const float* Wd    = (const float*)d_in[6];
    const float* bd    = (const float*)d_in[7];
    const float* h0    = (const float*)d_in[8];
    float* out = (float*)d_out;

    // workspace: WdT hi/lo (2+2 MB) + flags (8 KB)
    bf16* WdTh = (bf16*)d_ws;
    bf16* WdTl = WdTh + (size_t)D_DIM * D_DIM;
    int* flags = (int*)((char*)d_ws + (size_t)D_DIM * D_DIM * 4);

    hipMemsetAsync(flags, 0, 8192, stream);

    transpose_split<<<dim3(D_DIM / 32, D_DIM / 32), dim3(32, 8), 0, stream>>>(
        Wd, WdTh, WdTl, D_DIM, D_DIM);

    // GRU scan with fused input projections; packed h history -> d_out rows
    gru_scan<<<128, 256, 0, stream>>>(Wx, Wh, bx, bh, h0, embed, y,
                                      (uint32_t*)out, flags);

    // In-place: out rows = h rows @ Wd + bd
    gemm_rows_inplace<<<M_REAL / 32, 256, 0, stream>>>(out, WdTh, WdTl, bd);
}

// Round 6
// 7591.122 us; speedup vs baseline: 2.0317x; 1.0185x over previous
//
#include <hip/hip_runtime.h>
#include <hip/hip_bf16.h>
#include <cstdint>

typedef __bf16 bf16;
typedef __bf16 bf16x8 __attribute__((ext_vector_type(8)));
typedef float  f32x4  __attribute__((ext_vector_type(4)));
typedef uint32_t u32x4 __attribute__((ext_vector_type(4)));

#define D_DIM   1024
#define ND      3072
#define B_SZ    32
#define U_SZ    512
#define T_SZ    513
#define M_REAL  (B_SZ * T_SZ)   // 16416
#define WXS_LD  1032            // padded k-stride
#define A_LD    1032

#define AGENT __HIP_MEMORY_SCOPE_AGENT

__device__ __forceinline__ f32x4 mfma16(bf16x8 a, bf16x8 b, f32x4 c) {
    return __builtin_amdgcn_mfma_f32_16x16x32_bf16(a, b, c, 0, 0, 0);
}

struct bfpair { bf16x8 hi, lo; };

// split 8 consecutive fp32 into bf16 hi + bf16 residual lo
__device__ __forceinline__ bfpair split8(const float* p) {
    f32x4 a = *(const f32x4*)p;
    f32x4 b = *(const f32x4*)(p + 4);
    bfpair r;
#pragma unroll
    for (int j = 0; j < 4; ++j) {
        r.hi[j] = (bf16)a[j];
        r.lo[j] = (bf16)(a[j] - (float)r.hi[j]);
        r.hi[4 + j] = (bf16)b[j];
        r.lo[4 + j] = (bf16)(b[j] - (float)r.hi[4 + j]);
    }
    return r;
}

// convert 8 consecutive fp32 to bf16
__device__ __forceinline__ bf16x8 cvt8(const float* p) {
    f32x4 a = *(const f32x4*)p;
    f32x4 b = *(const f32x4*)(p + 4);
    bf16x8 r;
#pragma unroll
    for (int j = 0; j < 4; ++j) { r[j] = (bf16)a[j]; r[4 + j] = (bf16)b[j]; }
    return r;
}

// unpack 8 packed uint32 (hi bf16 | lo bf16 << 16) -> hi8, lo8 via v_perm
__device__ __forceinline__ bfpair unpack8(const uint32_t* p) {
    u32x4 a = *(const u32x4*)p;
    u32x4 b = *(const u32x4*)(p + 4);
    union { uint32_t u[4]; bf16x8 v; } H, L;
    H.u[0] = __builtin_amdgcn_perm(a.y, a.x, 0x05040100u);
    H.u[1] = __builtin_amdgcn_perm(a.w, a.z, 0x05040100u);
    H.u[2] = __builtin_amdgcn_perm(b.y, b.x, 0x05040100u);
    H.u[3] = __builtin_amdgcn_perm(b.w, b.z, 0x05040100u);
    L.u[0] = __builtin_amdgcn_perm(a.y, a.x, 0x07060302u);
    L.u[1] = __builtin_amdgcn_perm(a.w, a.z, 0x07060302u);
    L.u[2] = __builtin_amdgcn_perm(b.y, b.x, 0x07060302u);
    L.u[3] = __builtin_amdgcn_perm(b.w, b.z, 0x07060302u);
    bfpair r; r.hi = H.v; r.lo = L.v;
    return r;
}

// ---------------------------------------------------------------------------
// Transpose fp32 Wd [K][N] -> bf16 hi/lo planes WdT[N][K]
// ---------------------------------------------------------------------------
__global__ void transpose_split(const float* __restrict__ in,
                                bf16* __restrict__ out_hi, bf16* __restrict__ out_lo,
                                int R, int C) {
    __shared__ float tile[32][33];
    const int c0 = blockIdx.x * 32, r0 = blockIdx.y * 32;
    const int tx = threadIdx.x, ty = threadIdx.y;   // 32 x 8
    for (int i = 0; i < 32; i += 8)
        tile[ty + i][tx] = in[(size_t)(r0 + ty + i) * C + c0 + tx];
    __syncthreads();
    for (int i = 0; i < 32; i += 8) {
        const float v  = tile[tx][ty + i];
        const bf16  hi = (bf16)v;
        out_hi[(size_t)(c0 + ty + i) * R + r0 + tx] = hi;
        out_lo[(size_t)(c0 + ty + i) * R + r0 + tx] = (bf16)(v - (float)hi);
    }
}

// ---------------------------------------------------------------------------
// GRU scan. 128 persistent WGs x 256 threads; block = (mhalf, 16-dim slice).
//   Barrier (R6): zero-RMW. Arrive = relaxed store to a per-block slot
//   (16-B stride). Block 0 wave 0 sweeps all 128 slots in parallel (1 atomic
//   load/lane x2, __all-reduce => sweep ~ one MALL round trip), then stores
//   go=t+1 replicated on 8 lines; others spin on their go line. Monotonic
//   values, no resets, no fences, no same-line RMW serialization.
// ---------------------------------------------------------------------------
__global__ __launch_bounds__(256, 1)
void gru_scan(const float* __restrict__ Wx,    const float* __restrict__ Wh,
              const float* __restrict__ bx,    const float* __restrict__ bh,
              const float* __restrict__ h0,    const float* __restrict__ embed,
              const int* __restrict__ y,       uint32_t* __restrict__ ghs,
              int* __restrict__ flags)
{
    __shared__ __align__(16) bf16 WxS[48 * WXS_LD];  // [c = gate*16+cl][k]
    __shared__ float hpx[48 * 17];
    __shared__ float xpx[2][48 * 17];
    __shared__ float bhs[48], bxs[48];

    const int tid  = threadIdx.x;
    const int wave = tid >> 6, lane = tid & 63;
    const int quad = lane >> 4, l15 = lane & 15;
    const int mhalf = blockIdx.x & 1;
    const int n0 = (blockIdx.x >> 1) * 16;
    int* slots = flags;          // slot for block b at flags[b*4]  (16-B stride)
    int* go    = flags + 512;    // go line j at flags[512 + j*16], j=0..7

    // ---- one-time: gather Wx slice [48 cols][1024 k] from fp32 Wx[k][3D] ----
    for (int idx = tid; idx < 3 * 1024 * 16; idx += 256) {
        const int cl = idx & 15;
        const int k  = (idx >> 4) & 1023;
        const int g  = idx >> 14;            // 0..2
        WxS[(g * 16 + cl) * WXS_LD + k] = (bf16)Wx[(size_t)k * ND + g * D_DIM + n0 + cl];
    }
    if (tid < 48) {
        bhs[tid] = bh[(tid >> 4) * D_DIM + n0 + (tid & 15)];
        bxs[tid] = bx[(tid >> 4) * D_DIM + n0 + (tid & 15)];
    }

    // ---- one-time: gather Wh gate-slice into registers (waves 0..2) ----
    bf16x8 breg[32];
    if (wave < 3) {
#pragma unroll
        for (int ks = 0; ks < 32; ++ks) {
            bf16x8 v;
#pragma unroll
            for (int j = 0; j < 8; ++j)
                v[j] = (bf16)Wh[(size_t)(ks * 32 + quad * 8 + j) * ND
                                + wave * D_DIM + n0 + l15];
            breg[ks] = v;
        }
    }

    // gate-phase identity: one (batch, dim) output per thread
    const int gml = tid >> 4, nl = tid & 15;
    const int gb  = mhalf * 16 + gml;
    const int gn  = n0 + nl;
    float hold = h0[gn];
    uint32_t pkjunk = 0;

    __syncthreads();

    // ---- pre-loop: xp(0), all tokens NULL (embed row 0) -> xpx[0] ----
    if (wave == 3) {
        const float* xrow = embed + quad * 8;
        f32x4 ax0 = {}, ax1 = {}, ax2 = {};
#pragma unroll
        for (int ks = 0; ks < 32; ++ks) {
            bf16x8 xa = cvt8(xrow + ks * 32);
            bf16x8 w0 = *(const bf16x8*)(WxS + (l15)      * WXS_LD + ks * 32 + quad * 8);
            bf16x8 w1 = *(const bf16x8*)(WxS + (16 + l15) * WXS_LD + ks * 32 + quad * 8);
            bf16x8 w2 = *(const bf16x8*)(WxS + (32 + l15) * WXS_LD + ks * 32 + quad * 8);
            ax0 = mfma16(xa, w0, ax0);
            ax1 = mfma16(xa, w1, ax1);
            ax2 = mfma16(xa, w2, ax2);
        }
#pragma unroll
        for (int i = 0; i < 4; ++i) {
            xpx[0][(quad * 4 + i) * 17 + l15]      = ax0[i];
            xpx[0][(16 + quad * 4 + i) * 17 + l15] = ax1[i];
            xpx[0][(32 + quad * 4 + i) * 17 + l15] = ax2[i];
        }
    }

    for (int t = 0; t < T_SZ; ++t) {
        // ---- waves 0..2: hp = h_{t-1} @ Wh slice, split-precision A ----
        if (wave < 3) {
            f32x4 a0 = {}, a1 = {};
            if (t == 0) {
                const float* hrow = h0 + quad * 8;
#pragma unroll
                for (int ks = 0; ks < 32; ++ks) {
                    bfpair h8 = split8(hrow + ks * 32);
                    a0 = mfma16(h8.hi, breg[ks], a0);
                    a1 = mfma16(h8.lo, breg[ks], a1);
                }
            } else {
                const uint32_t* hrow = ghs
                    + ((size_t)(mhalf * 16 + l15) * T_SZ + (t - 1)) * D_DIM + quad * 8;
#pragma unroll
                for (int ks = 0; ks < 32; ++ks) {
                    bfpair h8 = unpack8(hrow + ks * 32);
                    a0 = mfma16(h8.hi, breg[ks], a0);
                    a1 = mfma16(h8.lo, breg[ks], a1);
                }
            }
            a0 = a0 + a1;
#pragma unroll
            for (int i = 0; i < 4; ++i)
                hpx[(wave * 16 + quad * 4 + i) * 17 + l15] = a0[i];
        }

        // ---- wave 3: xp(t+1), off critical path ----
        if (wave == 3 && t < U_SZ) {
            const int tok = y[(mhalf * 16 + l15) * U_SZ + t] & 1023;  // token at step t+1
            const float* xrow = embed + (size_t)tok * D_DIM + quad * 8;
            const int p = (t + 1) & 1;
            f32x4 ax0 = {}, ax1 = {}, ax2 = {};
#pragma unroll
            for (int ks = 0; ks < 32; ++ks) {
                bf16x8 xa = cvt8(xrow + ks * 32);
                bf16x8 w0 = *(const bf16x8*)(WxS + (l15)      * WXS_LD + ks * 32 + quad * 8);
                bf16x8 w1 = *(const bf16x8*)(WxS + (16 + l15) * WXS_LD + ks * 32 + quad * 8);
                bf16x8 w2 = *(const bf16x8*)(WxS + (32 + l15) * WXS_LD + ks * 32 + quad * 8);
                ax0 = mfma16(xa, w0, ax0);
                ax1 = mfma16(xa, w1, ax1);
                ax2 = mfma16(xa, w2, ax2);
            }
#pragma unroll
            for (int i = 0; i < 4; ++i) {
                xpx[p][(quad * 4 + i) * 17 + l15]      = ax0[i];
                xpx[p][(16 + quad * 4 + i) * 17 + l15] = ax1[i];
                xpx[p][(32 + quad * 4 + i) * 17 + l15] = ax2[i];
            }
        }
        __syncthreads();

        // ---- gates: one (gb, gn) per thread; publish packed hi/lo h ----
        {
            const int p = t & 1;
            const float xz = xpx[p][(gml)      * 17 + nl] + bxs[nl];
            const float xr = xpx[p][(16 + gml) * 17 + nl] + bxs[16 + nl];
            const float xh = xpx[p][(32 + gml) * 17 + nl] + bxs[32 + nl];
            const float hz = hpx[(gml)      * 17 + nl] + bhs[nl];
            const float hr = hpx[(16 + gml) * 17 + nl] + bhs[16 + nl];
            const float hh = hpx[(32 + gml) * 17 + nl] + bhs[32 + nl];
            const float z  = 1.f / (1.f + __expf(-(xz + hz)));
            const float r  = 1.f / (1.f + __expf(-(xr + hr)));
            const float pa = xh + r * hh;
            const float hc = 1.f - 2.f / (__expf(2.f * pa) + 1.f);   // tanh(pa)
            const float hn = z * hold + (1.f - z) * hc;
            hold = hn;
            union { uint16_t u[2]; uint32_t w; } pk;
            const bf16 hi = (bf16)hn;
            const bf16 lo = (bf16)(hn - (float)hi);
            pk.u[0] = __builtin_bit_cast(uint16_t, hi);
            pk.u[1] = __builtin_bit_cast(uint16_t, lo);
            uint32_t old = __hip_atomic_exchange(
                ghs + ((size_t)gb * T_SZ + t) * D_DIM + gn, pk.w,
                __ATOMIC_RELAXED, AGENT);
            pkjunk ^= old;
        }

        // ---- zero-RMW device barrier: publish h_t ----
        if (t + 1 < T_SZ) {
            __syncthreads();   // s_waitcnt vmcnt(0) first: drains exchanges
            const int tv = t + 1;
            if (blockIdx.x == 0) {
                if (wave == 0) {
                    // parallel sweep: lane covers slots {lane, lane+64};
                    // slot 0 is ourselves (arrived by construction)
                    int ok;
                    do {
                        const int s1 = __hip_atomic_load(slots + lane * 4,
                                                         __ATOMIC_RELAXED, AGENT);
                        const int s2 = __hip_atomic_load(slots + (lane + 64) * 4,
                                                         __ATOMIC_RELAXED, AGENT);
                        ok = (lane == 0 || s1 >= tv) && (s2 >= tv);
                    } while (!__all(ok));
                    if (lane < 8)
                        __hip_atomic_store(go + lane * 16, tv,
                                           __ATOMIC_RELAXED, AGENT);
                }
            } else {
                if (tid == 0) {
                    __hip_atomic_store(slots + blockIdx.x * 4, tv,
                                       __ATOMIC_RELAXED, AGENT);
                    while (__hip_atomic_load(go + (blockIdx.x & 7) * 16,
                                             __ATOMIC_RELAXED, AGENT) < tv) {}
                }
            }
            __syncthreads();
        }
    }

    // consume pkjunk so the exchanges keep their returning form
    if (pkjunk == 0xDEADBEEFu) flags[1023] = 1;
}

// ---------------------------------------------------------------------------
// In-place row-block GEMM: rows (packed hi/lo h) -> fp32 out rows.
// ---------------------------------------------------------------------------
__global__ __launch_bounds__(256, 1)
void gemm_rows_inplace(float* __restrict__ C,
                       const bf16* __restrict__ WdTh, const bf16* __restrict__ WdTl,
                       const float* __restrict__ bd)
{
    __shared__ __align__(16) bf16 Ah[32 * A_LD];
    __shared__ __align__(16) bf16 Al[32 * A_LD];
    const int tid  = threadIdx.x;
    const int wave = tid >> 6, lane = tid & 63;
    const int quad = lane >> 4, l15 = lane & 15;
    const size_t r0 = (size_t)blockIdx.x * 32;
    const uint32_t* Cw = (const uint32_t*)C;

    for (int idx = tid; idx < 32 * 128; idx += 256) {
        const int r = idx >> 7, ch = idx & 127;
        bfpair p = unpack8(Cw + (r0 + r) * D_DIM + ch * 8);
        *(bf16x8*)(Ah + r * A_LD + ch * 8) = p.hi;
        *(bf16x8*)(Al + r * A_LD + ch * 8) = p.lo;
    }
    __syncthreads();

    f32x4 acc[2][16] = {};
    const int nbase = wave * 256;
    for (int ks = 0; ks < 32; ++ks) {
        bf16x8 a0h = *(const bf16x8*)(Ah + (l15)      * A_LD + ks * 32 + quad * 8);
        bf16x8 a0l = *(const bf16x8*)(Al + (l15)      * A_LD + ks * 32 + quad * 8);
        bf16x8 a1h = *(const bf16x8*)(Ah + (16 + l15) * A_LD + ks * 32 + quad * 8);
        bf16x8 a1l = *(const bf16x8*)(Al + (16 + l15) * A_LD + ks * 32 + quad * 8);
#pragma unroll
        for (int nt = 0; nt < 16; ++nt) {
            const size_t boff = (size_t)(nbase + nt * 16 + l15) * D_DIM + ks * 32 + quad * 8;
            bf16x8 bhv = *(const bf16x8*)(WdTh + boff);
            bf16x8 blv = *(const bf16x8*)(WdTl + boff);
            acc[0][nt] = mfma16(a0h, bhv, acc[0][nt]);
            acc[0][nt] = mfma16(a0l, bhv, acc[0][nt]);
            acc[0][nt] = mfma16(a0h, blv, acc[0][nt]);
            acc[1][nt] = mfma16(a1h, bhv, acc[1][nt]);
            acc[1][nt] = mfma16(a1l, bhv, acc[1][nt]);
            acc[1][nt] = mfma16(a1h, blv, acc[1][nt]);
        }
    }

#pragma unroll
    for (int nt = 0; nt < 16; ++nt) {
        const int col = nbase + nt * 16 + l15;
        const float bvl = bd[col];
#pragma unroll
        for (int mt = 0; mt < 2; ++mt)
#pragma unroll
            for (int i = 0; i < 4; ++i)
                C[(r0 + mt * 16 + quad * 4 + i) * D_DIM + col] =
                    acc[mt][nt][i] + bvl;
    }
}

// ---------------------------------------------------------------------------
extern "C" void kernel_launch(void* const* d_in, const int* in_sizes, int n_in,
                              void* d_out, int out_size, void* d_ws, size_t ws_size,
                              hipStream_t stream) {
    (void)in_sizes; (void)n_in; (void)out_size; (void)ws_size;
    const int*   y     = (const int*)  d_in[0];
    const float* embed = (const float*)d_in[1];
    const float* Wx    = (const float*)d_in[2];
    const float* Wh    = (const float*)d_in[3];
    const float* bx    = (const float*)d_in[4];
    const float* bh    = (const float*)d_in[5];
    const float* Wd    = (const float*)d_in[6];
    const float* bd    = (const float*)d_in[7];
    const float* h0    = (const float*)d_in[8];
    float* out = (float*)d_out;

    // workspace: WdT hi/lo (2+2 MB) + flags (8 KB)
    bf16* WdTh = (bf16*)d_ws;
    bf16* WdTl = WdTh + (size_t)D_DIM * D_DIM;
    int* flags = (int*)((char*)d_ws + (size_t)D_DIM * D_DIM * 4);

    hipMemsetAsync(flags, 0, 8192, stream);

    transpose_split<<<dim3(D_DIM / 32, D_DIM / 32), dim3(32, 8), 0, stream>>>(
        Wd, WdTh, WdTl, D_DIM, D_DIM);

    // GRU scan with fused input projections; packed h history -> d_out rows
    gru_scan<<<128, 256, 0, stream>>>(Wx, Wh, bx, bh, h0, embed, y,
                                      (uint32_t*)out, flags);

    // In-place: out rows = h rows @ Wd + bd
    gemm_rows_inplace<<<M_REAL / 32, 256, 0, stream>>>(out, WdTh, WdTl, bd);
}